// Round 6
// baseline (570.599 us; speedup 1.0000x reference)
//
#include <hip/hip_runtime.h>

typedef unsigned short u16;
typedef unsigned int u32;
typedef __bf16 bf16x8 __attribute__((ext_vector_type(8)));
typedef float fx4 __attribute__((ext_vector_type(4)));

__device__ __forceinline__ float bf2f(u16 u) {
    return __uint_as_float(((u32)u) << 16);
}
__device__ __forceinline__ u16 f2bf(float f) {
    u32 x = __float_as_uint(f);
    u32 r = (x + 0x7fffu + ((x >> 16) & 1u)) >> 16;
    return (u16)r;
}

// async global->LDS, 16B per lane (gfx950). LDS dest must be linear:
// wave-uniform base + lane*16 (we pass per-lane ptrs equal to that).
__device__ __forceinline__ void gld16(const u16* g, u16* l) {
    __builtin_amdgcn_global_load_lds(
        (const __attribute__((address_space(1))) void*)g,
        (__attribute__((address_space(3))) void*)l, 16, 0, 0);
}

#define MFMA16(a, b, c) __builtin_amdgcn_mfma_f32_16x16x32_bf16((a), (b), (c), 0, 0, 0)

// ---------------------------------------------------------------------------
// fp32 -> bf16 bulk convert: x (8388608) | wqkv_w (12582912) | out_w (4194304)
// grid 12288 x 256, 8 elems/thread. Segment boundaries are block-aligned.
// ---------------------------------------------------------------------------
__global__ __launch_bounds__(256) void cvt_kernel(const float* __restrict__ x,
                                                  const float* __restrict__ w1,
                                                  const float* __restrict__ w2,
                                                  u16* __restrict__ xb,
                                                  u16* __restrict__ w1b,
                                                  u16* __restrict__ w2b) {
    size_t g = ((size_t)blockIdx.x * 256 + threadIdx.x) * 8;
    const float* src;
    u16* dst;
    if (g < 8388608) {
        src = x;
        dst = xb;
    } else if (g < 20971520) {
        src = w1 - 8388608;
        dst = w1b - 8388608;
    } else {
        src = w2 - 20971520;
        dst = w2b - 20971520;
    }
    float4 a = *(const float4*)&src[g];
    float4 b = *(const float4*)&src[g + 4];
    u16 v[8];
    v[0] = f2bf(a.x);
    v[1] = f2bf(a.y);
    v[2] = f2bf(a.z);
    v[3] = f2bf(a.w);
    v[4] = f2bf(b.x);
    v[5] = f2bf(b.y);
    v[6] = f2bf(b.z);
    v[7] = f2bf(b.w);
    *(uint4*)&dst[g] = *(const uint4*)v;
}

// ---------------------------------------------------------------------------
// GEMM (m97 structure): C[M][N] = A[M][K] * B[N][K]^T + bias[N]
// A, B bf16 row-major. 128x128 tile, BK=32, global_load_lds width 16,
// 2-barrier K-loop. LDS linear [128][32] with XOR-swizzled SOURCE cols
// (unit ^= (row>>1)&3) and the same XOR on ds_read -> 2-way conflicts (free).
// MODE 0: write fp32 Cf[M][N]. MODE 1: qkv scatter (bf16) to qb/kb/vb.
// ---------------------------------------------------------------------------
template <int MODE>
__global__ __launch_bounds__(256, 2) void gemm_bt(const u16* __restrict__ A,
                                                  const u16* __restrict__ B,
                                                  const float* __restrict__ bias,
                                                  float* __restrict__ Cf,
                                                  u16* __restrict__ qb,
                                                  u16* __restrict__ kb,
                                                  u16* __restrict__ vb,
                                                  int N, int K) {
    __shared__ __align__(16) u16 As[128 * 32];
    __shared__ __align__(16) u16 Bs[128 * 32];

    const int tid = threadIdx.x;
    const int lane = tid & 63;
    const int wave = tid >> 6;
    const int quad = lane >> 4;
    const int m16 = lane & 15;
    const int wm = wave >> 1, wn = wave & 1;
    const int bm = blockIdx.y * 128, bn = blockIdx.x * 128;

    const int r0 = tid >> 2;
    const int u0 = (tid & 3) ^ ((r0 >> 1) & 3);
    const int r1 = (tid + 256) >> 2;
    const int u1 = ((tid + 256) & 3) ^ ((r1 >> 1) & 3);
    const u16* a0 = &A[(size_t)(bm + r0) * K + u0 * 8];
    const u16* a1 = &A[(size_t)(bm + r1) * K + u1 * 8];
    const u16* b0 = &B[(size_t)(bn + r0) * K + u0 * 8];
    const u16* b1 = &B[(size_t)(bn + r1) * K + u1 * 8];
    u16* la0 = &As[tid * 8];
    u16* la1 = &As[(tid + 256) * 8];
    u16* lb0 = &Bs[tid * 8];
    u16* lb1 = &Bs[(tid + 256) * 8];

    const int su = (quad ^ ((m16 >> 1) & 3)) * 8;

    const fx4 zero4 = {0.f, 0.f, 0.f, 0.f};
    fx4 acc[4][4];
#pragma unroll
    for (int i = 0; i < 4; ++i)
#pragma unroll
        for (int j = 0; j < 4; ++j) acc[i][j] = zero4;

    const int nk = K >> 5;
    for (int kt = 0; kt < nk; ++kt) {
        const int k0 = kt << 5;
        gld16(a0 + k0, la0);
        gld16(a1 + k0, la1);
        gld16(b0 + k0, lb0);
        gld16(b1 + k0, lb1);
        __syncthreads();  // drains vmcnt -> tile resident
        bf16x8 af[4], bfr[4];
#pragma unroll
        for (int t = 0; t < 4; ++t) {
            af[t] = *(const bf16x8*)&As[(wm * 64 + t * 16 + m16) * 32 + su];
            bfr[t] = *(const bf16x8*)&Bs[(wn * 64 + t * 16 + m16) * 32 + su];
        }
#pragma unroll
        for (int mt = 0; mt < 4; ++mt)
#pragma unroll
            for (int nt = 0; nt < 4; ++nt)
                acc[mt][nt] = MFMA16(af[mt], bfr[nt], acc[mt][nt]);
        __syncthreads();  // all waves done reading before next stage
    }

#pragma unroll
    for (int mt = 0; mt < 4; ++mt) {
#pragma unroll
        for (int r = 0; r < 4; ++r) {
            int row = bm + wm * 64 + mt * 16 + quad * 4 + r;
#pragma unroll
            for (int nt = 0; nt < 4; ++nt) {
                int col = bn + wn * 64 + nt * 16 + m16;
                float v = acc[mt][nt][r] + bias[col];
                if (MODE == 0) {
                    Cf[(size_t)row * N + col] = v;
                } else {
                    int which = col >> 11;
                    int h = (col >> 7) & 15;
                    int d = col & 127;
                    int b = row >> 11;
                    int s = row & 2047;
                    u16* dst = (which == 0) ? qb : ((which == 1) ? kb : vb);
                    dst[(size_t)((b * 16 + h) * 2048 + s) * 128 + d] = f2bf(v);
                }
            }
        }
    }
}

// ---------------------------------------------------------------------------
// RoPE in place on q and k (bf16), layout [bh][s][128]; pair (i, i+64).
// ---------------------------------------------------------------------------
__global__ __launch_bounds__(256) void rope_kernel(u16* __restrict__ q,
                                                   u16* __restrict__ k) {
    int t = blockIdx.x * 256 + threadIdx.x;
    int i = t & 63;
    int s = (t >> 6) & 2047;
    int bh = t >> 17;
    float inv = exp2f(-(float)i * 0.2076205059304595f);  // 10000^(-i/64)
    float ang = (float)s * inv;
    float sn, cs;
    sincosf(ang, &sn, &cs);
    size_t base = ((size_t)bh * 2048 + s) * 128 + i;
    {
        float x1 = bf2f(q[base]), x2 = bf2f(q[base + 64]);
        q[base] = f2bf(x1 * cs - x2 * sn);
        q[base + 64] = f2bf(x1 * sn + x2 * cs);
    }
    {
        float x1 = bf2f(k[base]), x2 = bf2f(k[base + 64]);
        k[base] = f2bf(x1 * cs - x2 * sn);
        k[base + 64] = f2bf(x1 * sn + x2 * cs);
    }
}

// ---------------------------------------------------------------------------
// V transpose: [bh][s][d] -> [bh][d][s] (bf16 ws).
// ---------------------------------------------------------------------------
__global__ __launch_bounds__(256) void vtrans_kernel(const u16* __restrict__ v,
                                                     u16* __restrict__ vt) {
    __shared__ __align__(16) u16 L[128 * 66];
    const int tid = threadIdx.x;
    const int kb = blockIdx.x * 64;
    const int bh = blockIdx.y;
    const u16* vp = v + (size_t)bh * 2048 * 128;
    u16* op = vt + (size_t)bh * 128 * 2048;
#pragma unroll
    for (int i = 0; i < 4; ++i) {
        int c = i * 256 + tid;
        int t = c >> 4, d8 = (c & 15) << 3;
        uint4 x = *(const uint4*)&vp[(kb + t) * 128 + d8];
        const u16* xs = (const u16*)&x;
#pragma unroll
        for (int j = 0; j < 8; ++j) L[(d8 + j) * 66 + t] = xs[j];
    }
    __syncthreads();
#pragma unroll
    for (int i = 0; i < 4; ++i) {
        int c = i * 256 + tid;
        int d = c >> 3, t8 = (c & 7) << 3;
        uint4 x;
        u16* xs = (u16*)&x;
#pragma unroll
        for (int j = 0; j < 8; ++j) xs[j] = L[d * 66 + t8 + j];
        *(uint4*)&op[(size_t)d * 2048 + kb + t8] = x;
    }
}

// ---------------------------------------------------------------------------
// Flash attention (causal), placement-independent equal-work blocks.
// Each block: one 64-row half of Q-tile qt0 AND the same half of the
// complementary tile 15-qt0, processed as two sequential passes over the
// SAME (bh) K/V stream. Per-block staged K-tiles:
//   (2*qt0+1+half) + (2*(15-qt0)+1+half) = 32 + 2*half  -> equal work for
// every block regardless of CU placement (fixes the ~50% CU idle seen as
// OccupancyPercent 13% with exact-fill "paired" grids).
// Grid 512 = 2 halves x 8 pairs x 32 bh; adjacent ids share (qt0,bh) ->
// same-XCD L2 reuse of K/V.
// Structure per pass = R3's proven kernel: 256 thr / 4 waves, 1 frag
// (16 rows) per wave, single-buffer LDS + register prefetch (T14),
// XOR-swizzled Ks/Vs/Ps, shuffle online softmax, setprio on MFMA.
// LDS 40 KiB, ~100 VGPR -> 2 blocks/CU resident.
// q,k: [bh][s][128]; vt: [bh][d][s]; ctx: [b][s][h*128+d].
// ---------------------------------------------------------------------------
__global__ __launch_bounds__(256, 2) void attn_kernel(const u16* __restrict__ q,
                                                      const u16* __restrict__ k,
                                                      const u16* __restrict__ vt,
                                                      u16* __restrict__ ctx) {
    __shared__ __align__(16) u16 Ks[64 * 128];   // K [token][d], swizzled
    __shared__ __align__(16) u16 Vs[128 * 64];   // V^T [d][token], swizzled
    __shared__ __align__(16) u16 Ps[4][16 * 64]; // per-wave P 16x64, swizzled

    const int tid = threadIdx.x;
    const int lane = tid & 63;
    const int wave = tid >> 6;
    const int quad = lane >> 4;
    const int m16 = lane & 15;

    const int l = blockIdx.x;
    const int half = l & 1;
    const int qt0 = (l >> 1) & 7;
    const int bh = l >> 4;
    const int b = bh >> 4, h = bh & 15;
    const u16* qp = q + (size_t)bh * 2048 * 128;
    const u16* kp = k + (size_t)bh * 2048 * 128;
    const u16* vp = vt + (size_t)bh * 128 * 2048;
    const float scale = 0.08838834764831845f;  // 1/sqrt(128)
    const fx4 zero4 = {0.f, 0.f, 0.f, 0.f};

    // staging registers (register prefetch, depth 1)
    uint4 kr[4], vr[4];
    const int st_t = tid >> 4, st_d8 = (tid & 15) << 3;   // K slot
    const int st_dv = tid >> 3, st_t8 = (tid & 7) << 3;   // V slot

#define LOAD_TILE(kb_)                                                        \
    {                                                                         \
        _Pragma("unroll") for (int ii = 0; ii < 4; ++ii) {                    \
            kr[ii] = *(const uint4*)&kp[(size_t)((kb_) + st_t + ii * 16) *    \
                                            128 +                             \
                                        st_d8];                               \
            vr[ii] = *(const uint4*)&vp[(size_t)(st_dv + ii * 32) * 2048 +    \
                                        (kb_) + st_t8];                       \
        }                                                                     \
    }

#define STORE_TILE()                                                          \
    {                                                                         \
        _Pragma("unroll") for (int ii = 0; ii < 4; ++ii) {                    \
            int tt = st_t + ii * 16;                                          \
            int eK = tt * 128 + st_d8;                                        \
            *(uint4*)&Ks[eK ^ ((tt & 7) << 3)] = kr[ii];                      \
            int dv = st_dv + ii * 32;                                         \
            int eV = dv * 64 + st_t8;                                         \
            *(uint4*)&Vs[eV ^ ((dv & 7) << 3)] = vr[ii];                      \
        }                                                                     \
    }

#pragma unroll 1
    for (int pass = 0; pass < 2; ++pass) {
        const int qt = pass ? (15 - qt0) : qt0;
        const int qrow0 = qt * 128 + half * 64 + wave * 16;  // wave's 16 rows

        // Q fragment (A-layout: row=m16, k=c*32+quad*8+j)
        bf16x8 qf[4];
#pragma unroll
        for (int c = 0; c < 4; ++c)
            qf[c] = *(const bf16x8*)&qp[(size_t)(qrow0 + m16) * 128 + c * 32 +
                                        quad * 8];

        fx4 o[8];
#pragma unroll
        for (int dn = 0; dn < 8; ++dn) o[dn] = zero4;
        float mi[4], li[4];
#pragma unroll
        for (int r = 0; r < 4; ++r) {
            mi[r] = -1e30f;
            li[r] = 0.f;
        }

        // exact tile count for this 64-row half
        const int nkt = 2 * qt + 1 + half;
        LOAD_TILE(0);
        for (int kt = 0; kt < nkt; ++kt) {
            const int kb = kt * 64;
            STORE_TILE();
            __syncthreads();
            if (kt + 1 < nkt) LOAD_TILE(kb + 64);  // in flight under compute

            // QK^T: 16 rows x 64 cols
            fx4 sc[4];
#pragma unroll
            for (int nt = 0; nt < 4; ++nt) sc[nt] = zero4;
            __builtin_amdgcn_s_setprio(1);
#pragma unroll
            for (int c = 0; c < 4; ++c)
#pragma unroll
                for (int nt = 0; nt < 4; ++nt) {
                    int e = (nt * 16 + m16) * 128 + c * 32 + quad * 8;
                    bf16x8 kf = *(const bf16x8*)&Ks[e ^ ((m16 & 7) << 3)];
                    sc[nt] = MFMA16(qf[c], kf, sc[nt]);
                }
            __builtin_amdgcn_s_setprio(0);

            // shuffle online softmax (row = quad*4+r, its 16 cols on lanes
            // quad*16..quad*16+15; xor 1/2/4/8 stays inside the group)
#pragma unroll
            for (int r = 0; r < 4; ++r) {
                int rg = qrow0 + quad * 4 + r;
                float mx = mi[r];
#pragma unroll
                for (int nt = 0; nt < 4; ++nt) {
                    int cg = kb + nt * 16 + m16;
                    float s = sc[nt][r] * scale;
                    s = (cg <= rg) ? s : -1e30f;
                    sc[nt][r] = s;
                    mx = fmaxf(mx, s);
                }
                mx = fmaxf(mx, __shfl_xor(mx, 1));
                mx = fmaxf(mx, __shfl_xor(mx, 2));
                mx = fmaxf(mx, __shfl_xor(mx, 4));
                mx = fmaxf(mx, __shfl_xor(mx, 8));
                float alpha = __expf(mi[r] - mx);
                mi[r] = mx;
                float rsum = 0.f;
                int row = quad * 4 + r;
#pragma unroll
                for (int nt = 0; nt < 4; ++nt) {
                    float p = __expf(sc[nt][r] - mx);
                    Ps[wave][(row * 64 + nt * 16 + m16) ^ ((row & 7) << 3)] =
                        f2bf(p);
                    rsum += p;
                }
                rsum += __shfl_xor(rsum, 1);
                rsum += __shfl_xor(rsum, 2);
                rsum += __shfl_xor(rsum, 4);
                rsum += __shfl_xor(rsum, 8);
                li[r] = li[r] * alpha + rsum;
#pragma unroll
                for (int dn = 0; dn < 8; ++dn) o[dn][r] *= alpha;
            }

            // O += P * V. Ps wave-private: same-wave ds ordering suffices.
            __builtin_amdgcn_s_setprio(1);
#pragma unroll
            for (int c2 = 0; c2 < 2; ++c2) {
                bf16x8 pf = *(const bf16x8*)&Ps[wave][(m16 * 64 + c2 * 32 +
                                                       quad * 8) ^
                                                      ((m16 & 7) << 3)];
#pragma unroll
                for (int dn = 0; dn < 8; ++dn) {
                    int e = (dn * 16 + m16) * 64 + c2 * 32 + quad * 8;
                    bf16x8 vf = *(const bf16x8*)&Vs[e ^ ((m16 & 7) << 3)];
                    o[dn] = MFMA16(pf, vf, o[dn]);
                }
            }
            __builtin_amdgcn_s_setprio(0);

            __syncthreads();  // protect Ks/Vs before next staging
        }

        // epilogue for this pass's 16 rows
#pragma unroll
        for (int r = 0; r < 4; ++r) {
            int row = qrow0 + quad * 4 + r;
            float inv = 1.0f / li[r];
#pragma unroll
            for (int dn = 0; dn < 8; ++dn) {
                int d = dn * 16 + m16;
                ctx[((size_t)(b * 2048 + row)) * 2048 + h * 128 + d] =
                    f2bf(o[dn][r] * inv);
            }
        }
    }
}

// ---------------------------------------------------------------------------
// ws (64 MiB u16): xb 8388608 | wqkvb 12582912 | v/ctx 8388608 | outwb 4194304
// d_out (32 MiB used as scratch until final GEMM): q 8388608 | k 8388608
// vt reuses xb after the QKV GEMM. Final GEMM overwrites d_out (q,k dead).
// ---------------------------------------------------------------------------
extern "C" void kernel_launch(void* const* d_in, const int* in_sizes, int n_in,
                              void* d_out, int out_size, void* d_ws,
                              size_t ws_size, hipStream_t stream) {
    const float* x = (const float*)d_in[0];
    const float* wqkv_w = (const float*)d_in[1];
    const float* wqkv_b = (const float*)d_in[2];
    const float* out_w = (const float*)d_in[3];
    const float* out_b = (const float*)d_in[4];
    u16* ws = (u16*)d_ws;

    u16* xb = ws;                   // 8388608 u16 (later: vt)
    u16* wqkvb = ws + 8388608;      // 12582912 u16
    u16* vb = ws + 20971520;        // 8388608 u16 (later: ctx)
    u16* outwb = ws + 29360128;     // 4194304 u16
    u16* vtb = xb;
    u16* ctx = vb;
    u16* qb = (u16*)d_out;          // 8388608 u16
    u16* kb = qb + 8388608;         // 8388608 u16

    cvt_kernel<<<12288, 256, 0, stream>>>(x, wqkv_w, out_w, xb, wqkvb, outwb);
    gemm_bt<1><<<dim3(48, 32), 256, 0, stream>>>(xb, wqkvb, wqkv_b, nullptr,
                                                 qb, kb, vb, 6144, 2048);
    rope_kernel<<<16384, 256, 0, stream>>>(qb, kb);
    vtrans_kernel<<<dim3(32, 32), 256, 0, stream>>>(vb, vtb);
    attn_kernel<<<512, 256, 0, stream>>>(qb, kb, vtb, ctx);
    gemm_bt<0><<<dim3(16, 32), 256, 0, stream>>>(ctx, outwb, out_b,
                                                 (float*)d_out, nullptr,
                                                 nullptr, nullptr, 2048, 2048);
}

// Round 9
// 424.122 us; speedup vs baseline: 1.3454x; 1.3454x over previous
//
#include <hip/hip_runtime.h>

typedef unsigned short u16;
typedef unsigned int u32;
typedef __bf16 bf16x8 __attribute__((ext_vector_type(8)));
typedef float fx4 __attribute__((ext_vector_type(4)));

__device__ __forceinline__ float bf2f(u16 u) {
    return __uint_as_float(((u32)u) << 16);
}
__device__ __forceinline__ u16 f2bf(float f) {
    u32 x = __float_as_uint(f);
    u32 r = (x + 0x7fffu + ((x >> 16) & 1u)) >> 16;
    return (u16)r;
}

// async global->LDS, 16B per lane (gfx950). LDS dest must be linear:
// wave-uniform base + lane*16 (we pass per-lane ptrs equal to that).
__device__ __forceinline__ void gld16(const u16* g, u16* l) {
    __builtin_amdgcn_global_load_lds(
        (const __attribute__((address_space(1))) void*)g,
        (__attribute__((address_space(3))) void*)l, 16, 0, 0);
}

#define MFMA16(a, b, c) __builtin_amdgcn_mfma_f32_16x16x32_bf16((a), (b), (c), 0, 0, 0)

// ---------------------------------------------------------------------------
// fp32 -> bf16 bulk convert: x (8388608) | wqkv_w (12582912) | out_w (4194304)
// grid 12288 x 256, 8 elems/thread. Segment boundaries are block-aligned.
// ---------------------------------------------------------------------------
__global__ __launch_bounds__(256) void cvt_kernel(const float* __restrict__ x,
                                                  const float* __restrict__ w1,
                                                  const float* __restrict__ w2,
                                                  u16* __restrict__ xb,
                                                  u16* __restrict__ w1b,
                                                  u16* __restrict__ w2b) {
    size_t g = ((size_t)blockIdx.x * 256 + threadIdx.x) * 8;
    const float* src;
    u16* dst;
    if (g < 8388608) {
        src = x;
        dst = xb;
    } else if (g < 20971520) {
        src = w1 - 8388608;
        dst = w1b - 8388608;
    } else {
        src = w2 - 20971520;
        dst = w2b - 20971520;
    }
    float4 a = *(const float4*)&src[g];
    float4 b = *(const float4*)&src[g + 4];
    u16 v[8];
    v[0] = f2bf(a.x);
    v[1] = f2bf(a.y);
    v[2] = f2bf(a.z);
    v[3] = f2bf(a.w);
    v[4] = f2bf(b.x);
    v[5] = f2bf(b.y);
    v[6] = f2bf(b.z);
    v[7] = f2bf(b.w);
    *(uint4*)&dst[g] = *(const uint4*)v;
}

// ---------------------------------------------------------------------------
// GEMM (m97 structure): C[M][N] = A[M][K] * B[N][K]^T + bias[N]
// A, B bf16 row-major. 128x128 tile, BK=32, global_load_lds width 16,
// 2-barrier K-loop. LDS linear [128][32] with XOR-swizzled SOURCE cols
// (unit ^= (row>>1)&3) and the same XOR on ds_read -> 2-way conflicts (free).
// MODE 0: write fp32 Cf[M][N]. MODE 1: qkv scatter (bf16) to qb/kb/vb.
// ---------------------------------------------------------------------------
template <int MODE>
__global__ __launch_bounds__(256, 2) void gemm_bt(const u16* __restrict__ A,
                                                  const u16* __restrict__ B,
                                                  const float* __restrict__ bias,
                                                  float* __restrict__ Cf,
                                                  u16* __restrict__ qb,
                                                  u16* __restrict__ kb,
                                                  u16* __restrict__ vb,
                                                  int N, int K) {
    __shared__ __align__(16) u16 As[128 * 32];
    __shared__ __align__(16) u16 Bs[128 * 32];

    const int tid = threadIdx.x;
    const int lane = tid & 63;
    const int wave = tid >> 6;
    const int quad = lane >> 4;
    const int m16 = lane & 15;
    const int wm = wave >> 1, wn = wave & 1;
    const int bm = blockIdx.y * 128, bn = blockIdx.x * 128;

    const int r0 = tid >> 2;
    const int u0 = (tid & 3) ^ ((r0 >> 1) & 3);
    const int r1 = (tid + 256) >> 2;
    const int u1 = ((tid + 256) & 3) ^ ((r1 >> 1) & 3);
    const u16* a0 = &A[(size_t)(bm + r0) * K + u0 * 8];
    const u16* a1 = &A[(size_t)(bm + r1) * K + u1 * 8];
    const u16* b0 = &B[(size_t)(bn + r0) * K + u0 * 8];
    const u16* b1 = &B[(size_t)(bn + r1) * K + u1 * 8];
    u16* la0 = &As[tid * 8];
    u16* la1 = &As[(tid + 256) * 8];
    u16* lb0 = &Bs[tid * 8];
    u16* lb1 = &Bs[(tid + 256) * 8];

    const int su = (quad ^ ((m16 >> 1) & 3)) * 8;

    const fx4 zero4 = {0.f, 0.f, 0.f, 0.f};
    fx4 acc[4][4];
#pragma unroll
    for (int i = 0; i < 4; ++i)
#pragma unroll
        for (int j = 0; j < 4; ++j) acc[i][j] = zero4;

    const int nk = K >> 5;
    for (int kt = 0; kt < nk; ++kt) {
        const int k0 = kt << 5;
        gld16(a0 + k0, la0);
        gld16(a1 + k0, la1);
        gld16(b0 + k0, lb0);
        gld16(b1 + k0, lb1);
        __syncthreads();  // drains vmcnt -> tile resident
        bf16x8 af[4], bfr[4];
#pragma unroll
        for (int t = 0; t < 4; ++t) {
            af[t] = *(const bf16x8*)&As[(wm * 64 + t * 16 + m16) * 32 + su];
            bfr[t] = *(const bf16x8*)&Bs[(wn * 64 + t * 16 + m16) * 32 + su];
        }
#pragma unroll
        for (int mt = 0; mt < 4; ++mt)
#pragma unroll
            for (int nt = 0; nt < 4; ++nt)
                acc[mt][nt] = MFMA16(af[mt], bfr[nt], acc[mt][nt]);
        __syncthreads();  // all waves done reading before next stage
    }

#pragma unroll
    for (int mt = 0; mt < 4; ++mt) {
#pragma unroll
        for (int r = 0; r < 4; ++r) {
            int row = bm + wm * 64 + mt * 16 + quad * 4 + r;
#pragma unroll
            for (int nt = 0; nt < 4; ++nt) {
                int col = bn + wn * 64 + nt * 16 + m16;
                float v = acc[mt][nt][r] + bias[col];
                if (MODE == 0) {
                    Cf[(size_t)row * N + col] = v;
                } else {
                    int which = col >> 11;
                    int h = (col >> 7) & 15;
                    int d = col & 127;
                    int b = row >> 11;
                    int s = row & 2047;
                    u16* dst = (which == 0) ? qb : ((which == 1) ? kb : vb);
                    dst[(size_t)((b * 16 + h) * 2048 + s) * 128 + d] = f2bf(v);
                }
            }
        }
    }
}

// ---------------------------------------------------------------------------
// RoPE in place on q and k (bf16), layout [bh][s][128]; pair (i, i+64).
// ---------------------------------------------------------------------------
__global__ __launch_bounds__(256) void rope_kernel(u16* __restrict__ q,
                                                   u16* __restrict__ k) {
    int t = blockIdx.x * 256 + threadIdx.x;
    int i = t & 63;
    int s = (t >> 6) & 2047;
    int bh = t >> 17;
    float inv = exp2f(-(float)i * 0.2076205059304595f);  // 10000^(-i/64)
    float ang = (float)s * inv;
    float sn, cs;
    sincosf(ang, &sn, &cs);
    size_t base = ((size_t)bh * 2048 + s) * 128 + i;
    {
        float x1 = bf2f(q[base]), x2 = bf2f(q[base + 64]);
        q[base] = f2bf(x1 * cs - x2 * sn);
        q[base + 64] = f2bf(x1 * sn + x2 * cs);
    }
    {
        float x1 = bf2f(k[base]), x2 = bf2f(k[base + 64]);
        k[base] = f2bf(x1 * cs - x2 * sn);
        k[base + 64] = f2bf(x1 * sn + x2 * cs);
    }
}

// ---------------------------------------------------------------------------
// V transpose: [bh][s][d] -> [bh][d][s] (bf16 ws).
// ---------------------------------------------------------------------------
__global__ __launch_bounds__(256) void vtrans_kernel(const u16* __restrict__ v,
                                                     u16* __restrict__ vt) {
    __shared__ __align__(16) u16 L[128 * 66];
    const int tid = threadIdx.x;
    const int kb = blockIdx.x * 64;
    const int bh = blockIdx.y;
    const u16* vp = v + (size_t)bh * 2048 * 128;
    u16* op = vt + (size_t)bh * 128 * 2048;
#pragma unroll
    for (int i = 0; i < 4; ++i) {
        int c = i * 256 + tid;
        int t = c >> 4, d8 = (c & 15) << 3;
        uint4 x = *(const uint4*)&vp[(kb + t) * 128 + d8];
        const u16* xs = (const u16*)&x;
#pragma unroll
        for (int j = 0; j < 8; ++j) L[(d8 + j) * 66 + t] = xs[j];
    }
    __syncthreads();
#pragma unroll
    for (int i = 0; i < 4; ++i) {
        int c = i * 256 + tid;
        int d = c >> 3, t8 = (c & 7) << 3;
        uint4 x;
        u16* xs = (u16*)&x;
#pragma unroll
        for (int j = 0; j < 8; ++j) xs[j] = L[d * 66 + t8 + j];
        *(uint4*)&op[(size_t)d * 2048 + kb + t8] = x;
    }
}

// ---------------------------------------------------------------------------
// Flash attention (causal), equal-work blocks, spill-free staging.
// Each block: pass0 = 64-row half h of Q-tile qt0; pass1 = half (1-h) of
// tile 15-qt0. Staged K-tiles = (2qt0+1+h)+(31-2qt0+1-h) = 33 exactly ->
// placement-independent balance (R6's fix, kept).
// Staging: global_load_lds (zero data VGPRs -> kills the R4/R5/R6 scratch
// spill, WRITE_SIZE 534 MB) into DOUBLE-BUFFERED Ks/Vs. Swizzle moved to
// the global SOURCE address (rule #21): slot s -> row r, phys unit p,
// source unit p^(r&7); read side XORs the same involution. One barrier
// per tile; the 8 gld16/thread issued at tile top fly under the whole
// compute phase (T3 minimum-2-phase).
// Grid 512 = 2 halves x 8 pairs x 32 bh; adjacent ids share (qt0,bh).
// LDS: Ks 2x16K + Vs 2x16K + Ps 8K = 72 KiB -> 2 blocks/CU.
// q,k: [bh][s][128]; vt: [bh][d][s]; ctx: [b][s][h*128+d].
// ---------------------------------------------------------------------------
__global__ __launch_bounds__(256, 2) void attn_kernel(const u16* __restrict__ q,
                                                      const u16* __restrict__ k,
                                                      const u16* __restrict__ vt,
                                                      u16* __restrict__ ctx) {
    __shared__ __align__(16) u16 Ks[2][64 * 128];   // K [token][d], src-swz
    __shared__ __align__(16) u16 Vs[2][128 * 64];   // V^T [d][token], src-swz
    __shared__ __align__(16) u16 Ps[4][16 * 64];    // per-wave P, swizzled

    const int tid = threadIdx.x;
    const int lane = tid & 63;
    const int wave = tid >> 6;
    const int quad = lane >> 4;
    const int m16 = lane & 15;

    const int l = blockIdx.x;
    const int half0 = l & 1;
    const int qt0 = (l >> 1) & 7;
    const int bh = l >> 4;
    const int b = bh >> 4, h = bh & 15;
    const u16* qp = q + (size_t)bh * 2048 * 128;
    const u16* kp = k + (size_t)bh * 2048 * 128;
    const u16* vp = vt + (size_t)bh * 128 * 2048;
    const float scale = 0.08838834764831845f;  // 1/sqrt(128)
    const fx4 zero4 = {0.f, 0.f, 0.f, 0.f};

    // staging geometry: 4 K-slots + 4 V-slots per thread per tile.
    // K slot s = tid+i*256: row r=s>>4, phys unit p=s&15, src unit p^(r&7).
    // V slot s = tid+i*256: row d=s>>3, phys unit p=s&7,  src unit p^(d&7).
    // LDS dest is linear slot*16B (wave-uniform base + lane*16 per gld16).
    int ksrc[4], vsrc[4];
#pragma unroll
    for (int i = 0; i < 4; ++i) {
        int s = tid + i * 256;
        int r = s >> 4, p = s & 15;
        ksrc[i] = r * 128 + (p ^ (r & 7)) * 8;
        int d = s >> 3, pv = s & 7;
        vsrc[i] = d * 2048 + (pv ^ (d & 7)) * 8;
    }

#define GLD_TILE(kb_, buf_)                                                   \
    {                                                                         \
        _Pragma("unroll") for (int ii = 0; ii < 4; ++ii) {                    \
            gld16(kp + (size_t)(kb_)*128 + ksrc[ii],                          \
                  &Ks[buf_][tid * 8 + ii * 2048]);                            \
            gld16(vp + (kb_) + vsrc[ii], &Vs[buf_][tid * 8 + ii * 2048]);     \
        }                                                                     \
    }

#pragma unroll 1
    for (int pass = 0; pass < 2; ++pass) {
        const int qt = pass ? (15 - qt0) : qt0;
        const int hf = pass ? (1 - half0) : half0;
        const int qrow0 = qt * 128 + hf * 64 + wave * 16;  // wave's 16 rows
        const int nkt = 2 * qt + 1 + hf;

        // Q fragment (A-layout: row=m16, k=c*32+quad*8+j)
        bf16x8 qf[4];
#pragma unroll
        for (int c = 0; c < 4; ++c)
            qf[c] = *(const bf16x8*)&qp[(size_t)(qrow0 + m16) * 128 + c * 32 +
                                        quad * 8];

        fx4 o[8];
#pragma unroll
        for (int dn = 0; dn < 8; ++dn) o[dn] = zero4;
        float mi[4], li[4];
#pragma unroll
        for (int r = 0; r < 4; ++r) {
            mi[r] = -1e30f;
            li[r] = 0.f;
        }

        GLD_TILE(0, 0);
        __syncthreads();  // tile 0 resident
        int cur = 0;
        for (int kt = 0; kt < nkt; ++kt) {
            const int kb = kt * 64;
            // prefetch tile kt+1 into the idle buffer (flies under compute)
            if (kt + 1 < nkt) GLD_TILE(kb + 64, cur ^ 1);

            // QK^T: 16 rows x 64 cols
            fx4 sc[4];
#pragma unroll
            for (int nt = 0; nt < 4; ++nt) sc[nt] = zero4;
            __builtin_amdgcn_s_setprio(1);
#pragma unroll
            for (int c = 0; c < 4; ++c)
#pragma unroll
                for (int nt = 0; nt < 4; ++nt) {
                    int e = (nt * 16 + m16) * 128 + c * 32 + quad * 8;
                    bf16x8 kf =
                        *(const bf16x8*)&Ks[cur][e ^ ((m16 & 7) << 3)];
                    sc[nt] = MFMA16(qf[c], kf, sc[nt]);
                }
            __builtin_amdgcn_s_setprio(0);

            // shuffle online softmax (row = quad*4+r, its 16 cols on lanes
            // quad*16..quad*16+15; xor 1/2/4/8 stays inside the group)
#pragma unroll
            for (int r = 0; r < 4; ++r) {
                int rg = qrow0 + quad * 4 + r;
                float mx = mi[r];
#pragma unroll
                for (int nt = 0; nt < 4; ++nt) {
                    int cg = kb + nt * 16 + m16;
                    float s = sc[nt][r] * scale;
                    s = (cg <= rg) ? s : -1e30f;
                    sc[nt][r] = s;
                    mx = fmaxf(mx, s);
                }
                mx = fmaxf(mx, __shfl_xor(mx, 1));
                mx = fmaxf(mx, __shfl_xor(mx, 2));
                mx = fmaxf(mx, __shfl_xor(mx, 4));
                mx = fmaxf(mx, __shfl_xor(mx, 8));
                float alpha = __expf(mi[r] - mx);
                mi[r] = mx;
                float rsum = 0.f;
                int row = quad * 4 + r;
#pragma unroll
                for (int nt = 0; nt < 4; ++nt) {
                    float p = __expf(sc[nt][r] - mx);
                    Ps[wave][(row * 64 + nt * 16 + m16) ^ ((row & 7) << 3)] =
                        f2bf(p);
                    rsum += p;
                }
                rsum += __shfl_xor(rsum, 1);
                rsum += __shfl_xor(rsum, 2);
                rsum += __shfl_xor(rsum, 4);
                rsum += __shfl_xor(rsum, 8);
                li[r] = li[r] * alpha + rsum;
#pragma unroll
                for (int dn = 0; dn < 8; ++dn) o[dn][r] *= alpha;
            }

            // O += P * V. Ps wave-private: same-wave ds ordering suffices.
            __builtin_amdgcn_s_setprio(1);
#pragma unroll
            for (int c2 = 0; c2 < 2; ++c2) {
                bf16x8 pf = *(const bf16x8*)&Ps[wave][(m16 * 64 + c2 * 32 +
                                                       quad * 8) ^
                                                      ((m16 & 7) << 3)];
#pragma unroll
                for (int dn = 0; dn < 8; ++dn) {
                    int e = (dn * 16 + m16) * 64 + c2 * 32 + quad * 8;
                    bf16x8 vf =
                        *(const bf16x8*)&Vs[cur][e ^ ((m16 & 7) << 3)];
                    o[dn] = MFMA16(pf, vf, o[dn]);
                }
            }
            __builtin_amdgcn_s_setprio(0);

            __syncthreads();  // drains prefetch; ends reads of buf cur
            cur ^= 1;
        }

        // epilogue for this pass's 16 rows
#pragma unroll
        for (int r = 0; r < 4; ++r) {
            int row = qrow0 + quad * 4 + r;
            float inv = 1.0f / li[r];
#pragma unroll
            for (int dn = 0; dn < 8; ++dn) {
                int d = dn * 16 + m16;
                ctx[((size_t)(b * 2048 + row)) * 2048 + h * 128 + d] =
                    f2bf(o[dn][r] * inv);
            }
        }
    }
}

// ---------------------------------------------------------------------------
// ws (64 MiB u16): xb 8388608 | wqkvb 12582912 | v/ctx 8388608 | outwb 4194304
// d_out (32 MiB used as scratch until final GEMM): q 8388608 | k 8388608
// vt reuses xb after the QKV GEMM. Final GEMM overwrites d_out (q,k dead).
// ---------------------------------------------------------------------------
extern "C" void kernel_launch(void* const* d_in, const int* in_sizes, int n_in,
                              void* d_out, int out_size, void* d_ws,
                              size_t ws_size, hipStream_t stream) {
    const float* x = (const float*)d_in[0];
    const float* wqkv_w = (const float*)d_in[1];
    const float* wqkv_b = (const float*)d_in[2];
    const float* out_w = (const float*)d_in[3];
    const float* out_b = (const float*)d_in[4];
    u16* ws = (u16*)d_ws;

    u16* xb = ws;                   // 8388608 u16 (later: vt)
    u16* wqkvb = ws + 8388608;      // 12582912 u16
    u16* vb = ws + 20971520;        // 8388608 u16 (later: ctx)
    u16* outwb = ws + 29360128;     // 4194304 u16
    u16* vtb = xb;
    u16* ctx = vb;
    u16* qb = (u16*)d_out;          // 8388608 u16
    u16* kb = qb + 8388608;         // 8388608 u16

    cvt_kernel<<<12288, 256, 0, stream>>>(x, wqkv_w, out_w, xb, wqkvb, outwb);
    gemm_bt<1><<<dim3(48, 32), 256, 0, stream>>>(xb, wqkvb, wqkv_b, nullptr,
                                                 qb, kb, vb, 6144, 2048);
    rope_kernel<<<16384, 256, 0, stream>>>(qb, kb);
    vtrans_kernel<<<dim3(32, 32), 256, 0, stream>>>(vb, vtb);
    attn_kernel<<<512, 256, 0, stream>>>(qb, kb, vtb, ctx);
    gemm_bt<0><<<dim3(16, 32), 256, 0, stream>>>(ctx, outwb, out_b,
                                                 (float*)d_out, nullptr,
                                                 nullptr, nullptr, 2048, 2048);
}

// Round 10
// 414.987 us; speedup vs baseline: 1.3750x; 1.0220x over previous
//
#include <hip/hip_runtime.h>

typedef unsigned short u16;
typedef unsigned int u32;
typedef __bf16 bf16x8 __attribute__((ext_vector_type(8)));
typedef float fx4 __attribute__((ext_vector_type(4)));

__device__ __forceinline__ float bf2f(u16 u) {
    return __uint_as_float(((u32)u) << 16);
}
__device__ __forceinline__ u16 f2bf(float f) {
    u32 x = __float_as_uint(f);
    u32 r = (x + 0x7fffu + ((x >> 16) & 1u)) >> 16;
    return (u16)r;
}

// async global->LDS, 16B per lane (gfx950). LDS dest must be linear:
// wave-uniform base + lane*16 (we pass per-lane ptrs equal to that).
__device__ __forceinline__ void gld16(const u16* g, u16* l) {
    __builtin_amdgcn_global_load_lds(
        (const __attribute__((address_space(1))) void*)g,
        (__attribute__((address_space(3))) void*)l, 16, 0, 0);
}

#define MFMA16(a, b, c) __builtin_amdgcn_mfma_f32_16x16x32_bf16((a), (b), (c), 0, 0, 0)

// ---------------------------------------------------------------------------
// fp32 -> bf16 bulk convert: x (8388608) | wqkv_w (12582912) | out_w (4194304)
// grid 12288 x 256, 8 elems/thread. Segment boundaries are block-aligned.
// ---------------------------------------------------------------------------
__global__ __launch_bounds__(256) void cvt_kernel(const float* __restrict__ x,
                                                  const float* __restrict__ w1,
                                                  const float* __restrict__ w2,
                                                  u16* __restrict__ xb,
                                                  u16* __restrict__ w1b,
                                                  u16* __restrict__ w2b) {
    size_t g = ((size_t)blockIdx.x * 256 + threadIdx.x) * 8;
    const float* src;
    u16* dst;
    if (g < 8388608) {
        src = x;
        dst = xb;
    } else if (g < 20971520) {
        src = w1 - 8388608;
        dst = w1b - 8388608;
    } else {
        src = w2 - 20971520;
        dst = w2b - 20971520;
    }
    float4 a = *(const float4*)&src[g];
    float4 b = *(const float4*)&src[g + 4];
    u16 v[8];
    v[0] = f2bf(a.x);
    v[1] = f2bf(a.y);
    v[2] = f2bf(a.z);
    v[3] = f2bf(a.w);
    v[4] = f2bf(b.x);
    v[5] = f2bf(b.y);
    v[6] = f2bf(b.z);
    v[7] = f2bf(b.w);
    *(uint4*)&dst[g] = *(const uint4*)v;
}

// ---------------------------------------------------------------------------
// GEMM (m97 structure + counted-vmcnt dbuf, T4): C = A * B^T + bias.
// A, B bf16 row-major. 128x128 tile, BK=32, global_load_lds width 16.
// LDS DOUBLE-BUFFERED [2][128][32]; raw s_barrier + s_waitcnt vmcnt(4)
// (never 0 mid-loop) so the next tile's 4 loads stay in flight across the
// barrier (removes the __syncthreads vmcnt(0) drain = the ~20% stall).
// Per tile: ds_read frags -> 16 MFMA -> sched_barrier(0)+lgkmcnt(0)+barrier
// -> issue GLD(kt+2 -> buf[cur]) -> vmcnt(4) -> barrier -> cur^=1.
// Source-col XOR swizzle (unit ^= (row>>1)&3) + same XOR on ds_read ->
// 2-way conflicts (free, measured 0).
// MODE 0: write fp32 Cf[M][N]. MODE 1: qkv scatter (bf16) to qb/kb/vb.
// ---------------------------------------------------------------------------
template <int MODE>
__global__ __launch_bounds__(256, 2) void gemm_bt(const u16* __restrict__ A,
                                                  const u16* __restrict__ B,
                                                  const float* __restrict__ bias,
                                                  float* __restrict__ Cf,
                                                  u16* __restrict__ qb,
                                                  u16* __restrict__ kb,
                                                  u16* __restrict__ vb,
                                                  int N, int K) {
    __shared__ __align__(16) u16 As[2][128 * 32];
    __shared__ __align__(16) u16 Bs[2][128 * 32];

    const int tid = threadIdx.x;
    const int lane = tid & 63;
    const int wave = tid >> 6;
    const int quad = lane >> 4;
    const int m16 = lane & 15;
    const int wm = wave >> 1, wn = wave & 1;
    const int bm = blockIdx.y * 128, bn = blockIdx.x * 128;

    const int r0 = tid >> 2;
    const int u0 = (tid & 3) ^ ((r0 >> 1) & 3);
    const int r1 = (tid + 256) >> 2;
    const int u1 = ((tid + 256) & 3) ^ ((r1 >> 1) & 3);
    const u16* a0 = &A[(size_t)(bm + r0) * K + u0 * 8];
    const u16* a1 = &A[(size_t)(bm + r1) * K + u1 * 8];
    const u16* b0 = &B[(size_t)(bn + r0) * K + u0 * 8];
    const u16* b1 = &B[(size_t)(bn + r1) * K + u1 * 8];

    const int su = (quad ^ ((m16 >> 1) & 3)) * 8;

#define GLDT(kt_, buf_)                                                       \
    {                                                                         \
        const int k0_ = (kt_) << 5;                                           \
        gld16(a0 + k0_, &As[buf_][tid * 8]);                                  \
        gld16(a1 + k0_, &As[buf_][(tid + 256) * 8]);                          \
        gld16(b0 + k0_, &Bs[buf_][tid * 8]);                                  \
        gld16(b1 + k0_, &Bs[buf_][(tid + 256) * 8]);                          \
    }

    const fx4 zero4 = {0.f, 0.f, 0.f, 0.f};
    fx4 acc[4][4];
#pragma unroll
    for (int i = 0; i < 4; ++i)
#pragma unroll
        for (int j = 0; j < 4; ++j) acc[i][j] = zero4;

    const int nk = K >> 5;
    // prologue: tiles 0 and 1 in flight; wait for tile 0 only.
    GLDT(0, 0);
    if (nk > 1) {
        GLDT(1, 1);
        asm volatile("s_waitcnt vmcnt(4)" ::: "memory");
    } else {
        asm volatile("s_waitcnt vmcnt(0)" ::: "memory");
    }
    __builtin_amdgcn_s_barrier();

    int cur = 0;
    for (int kt = 0; kt < nk; ++kt) {
        bf16x8 af[4], bfr[4];
#pragma unroll
        for (int t = 0; t < 4; ++t) {
            af[t] = *(const bf16x8*)&As[cur][(wm * 64 + t * 16 + m16) * 32 + su];
            bfr[t] = *(const bf16x8*)&Bs[cur][(wn * 64 + t * 16 + m16) * 32 + su];
        }
        __builtin_amdgcn_s_setprio(1);
#pragma unroll
        for (int mt = 0; mt < 4; ++mt)
#pragma unroll
            for (int nt = 0; nt < 4; ++nt)
                acc[mt][nt] = MFMA16(af[mt], bfr[nt], acc[mt][nt]);
        __builtin_amdgcn_s_setprio(0);
        // pin MFMA + its lgkmcnt above the barrier (reg-only ops can sink
        // past asm barriers; outstanding ds_reads would race the GLD below)
        __builtin_amdgcn_sched_barrier(0);
        asm volatile("s_waitcnt lgkmcnt(0)" ::: "memory");
        __builtin_amdgcn_s_barrier();  // all waves done reading buf[cur]

        if (kt + 2 < nk) {
            GLDT(kt + 2, cur);  // reuse the buffer just vacated
            asm volatile("s_waitcnt vmcnt(4)" ::: "memory");  // tile kt+1 in
        } else {
            asm volatile("s_waitcnt vmcnt(0)" ::: "memory");
        }
        __builtin_amdgcn_s_barrier();  // tile kt+1 resident for everyone
        cur ^= 1;
    }

#pragma unroll
    for (int mt = 0; mt < 4; ++mt) {
#pragma unroll
        for (int r = 0; r < 4; ++r) {
            int row = bm + wm * 64 + mt * 16 + quad * 4 + r;
#pragma unroll
            for (int nt = 0; nt < 4; ++nt) {
                int col = bn + wn * 64 + nt * 16 + m16;
                float v = acc[mt][nt][r] + bias[col];
                if (MODE == 0) {
                    Cf[(size_t)row * N + col] = v;
                } else {
                    int which = col >> 11;
                    int h = (col >> 7) & 15;
                    int d = col & 127;
                    int b = row >> 11;
                    int s = row & 2047;
                    u16* dst = (which == 0) ? qb : ((which == 1) ? kb : vb);
                    dst[(size_t)((b * 16 + h) * 2048 + s) * 128 + d] = f2bf(v);
                }
            }
        }
    }
}

// ---------------------------------------------------------------------------
// RoPE in place on q and k (bf16), layout [bh][s][128]; pair (i, i+64).
// ---------------------------------------------------------------------------
__global__ __launch_bounds__(256) void rope_kernel(u16* __restrict__ q,
                                                   u16* __restrict__ k) {
    int t = blockIdx.x * 256 + threadIdx.x;
    int i = t & 63;
    int s = (t >> 6) & 2047;
    int bh = t >> 17;
    float inv = exp2f(-(float)i * 0.2076205059304595f);  // 10000^(-i/64)
    float ang = (float)s * inv;
    float sn, cs;
    sincosf(ang, &sn, &cs);
    size_t base = ((size_t)bh * 2048 + s) * 128 + i;
    {
        float x1 = bf2f(q[base]), x2 = bf2f(q[base + 64]);
        q[base] = f2bf(x1 * cs - x2 * sn);
        q[base + 64] = f2bf(x1 * sn + x2 * cs);
    }
    {
        float x1 = bf2f(k[base]), x2 = bf2f(k[base + 64]);
        k[base] = f2bf(x1 * cs - x2 * sn);
        k[base + 64] = f2bf(x1 * sn + x2 * cs);
    }
}

// ---------------------------------------------------------------------------
// V transpose: [bh][s][d] -> [bh][d][s] (bf16 ws).
// ---------------------------------------------------------------------------
__global__ __launch_bounds__(256) void vtrans_kernel(const u16* __restrict__ v,
                                                     u16* __restrict__ vt) {
    __shared__ __align__(16) u16 L[128 * 66];
    const int tid = threadIdx.x;
    const int kb = blockIdx.x * 64;
    const int bh = blockIdx.y;
    const u16* vp = v + (size_t)bh * 2048 * 128;
    u16* op = vt + (size_t)bh * 128 * 2048;
#pragma unroll
    for (int i = 0; i < 4; ++i) {
        int c = i * 256 + tid;
        int t = c >> 4, d8 = (c & 15) << 3;
        uint4 x = *(const uint4*)&vp[(kb + t) * 128 + d8];
        const u16* xs = (const u16*)&x;
#pragma unroll
        for (int j = 0; j < 8; ++j) L[(d8 + j) * 66 + t] = xs[j];
    }
    __syncthreads();
#pragma unroll
    for (int i = 0; i < 4; ++i) {
        int c = i * 256 + tid;
        int d = c >> 3, t8 = (c & 7) << 3;
        uint4 x;
        u16* xs = (u16*)&x;
#pragma unroll
        for (int j = 0; j < 8; ++j) xs[j] = L[d * 66 + t8 + j];
        *(uint4*)&op[(size_t)d * 2048 + kb + t8] = x;
    }
}

// ---------------------------------------------------------------------------
// Flash attention (causal), equal-work blocks, spill-free staging.
// (Unchanged from R9 — validated at <134 us, no spill.)
// Each block: pass0 = 64-row half h of Q-tile qt0; pass1 = half (1-h) of
// tile 15-qt0 -> 33 staged K-tiles per block exactly.
// Staging: global_load_lds into double-buffered Ks/Vs; source-swizzled.
// ---------------------------------------------------------------------------
__global__ __launch_bounds__(256, 2) void attn_kernel(const u16* __restrict__ q,
                                                      const u16* __restrict__ k,
                                                      const u16* __restrict__ vt,
                                                      u16* __restrict__ ctx) {
    __shared__ __align__(16) u16 Ks[2][64 * 128];   // K [token][d], src-swz
    __shared__ __align__(16) u16 Vs[2][128 * 64];   // V^T [d][token], src-swz
    __shared__ __align__(16) u16 Ps[4][16 * 64];    // per-wave P, swizzled

    const int tid = threadIdx.x;
    const int lane = tid & 63;
    const int wave = tid >> 6;
    const int quad = lane >> 4;
    const int m16 = lane & 15;

    const int l = blockIdx.x;
    const int half0 = l & 1;
    const int qt0 = (l >> 1) & 7;
    const int bh = l >> 4;
    const int b = bh >> 4, h = bh & 15;
    const u16* qp = q + (size_t)bh * 2048 * 128;
    const u16* kp = k + (size_t)bh * 2048 * 128;
    const u16* vp = vt + (size_t)bh * 128 * 2048;
    const float scale = 0.08838834764831845f;  // 1/sqrt(128)
    const fx4 zero4 = {0.f, 0.f, 0.f, 0.f};

    int ksrc[4], vsrc[4];
#pragma unroll
    for (int i = 0; i < 4; ++i) {
        int s = tid + i * 256;
        int r = s >> 4, p = s & 15;
        ksrc[i] = r * 128 + (p ^ (r & 7)) * 8;
        int d = s >> 3, pv = s & 7;
        vsrc[i] = d * 2048 + (pv ^ (d & 7)) * 8;
    }

#define GLD_TILE(kb_, buf_)                                                   \
    {                                                                         \
        _Pragma("unroll") for (int ii = 0; ii < 4; ++ii) {                    \
            gld16(kp + (size_t)(kb_)*128 + ksrc[ii],                          \
                  &Ks[buf_][tid * 8 + ii * 2048]);                            \
            gld16(vp + (kb_) + vsrc[ii], &Vs[buf_][tid * 8 + ii * 2048]);     \
        }                                                                     \
    }

#pragma unroll 1
    for (int pass = 0; pass < 2; ++pass) {
        const int qt = pass ? (15 - qt0) : qt0;
        const int hf = pass ? (1 - half0) : half0;
        const int qrow0 = qt * 128 + hf * 64 + wave * 16;  // wave's 16 rows
        const int nkt = 2 * qt + 1 + hf;

        // Q fragment (A-layout: row=m16, k=c*32+quad*8+j)
        bf16x8 qf[4];
#pragma unroll
        for (int c = 0; c < 4; ++c)
            qf[c] = *(const bf16x8*)&qp[(size_t)(qrow0 + m16) * 128 + c * 32 +
                                        quad * 8];

        fx4 o[8];
#pragma unroll
        for (int dn = 0; dn < 8; ++dn) o[dn] = zero4;
        float mi[4], li[4];
#pragma unroll
        for (int r = 0; r < 4; ++r) {
            mi[r] = -1e30f;
            li[r] = 0.f;
        }

        GLD_TILE(0, 0);
        __syncthreads();  // tile 0 resident
        int cur = 0;
        for (int kt = 0; kt < nkt; ++kt) {
            const int kb = kt * 64;
            // prefetch tile kt+1 into the idle buffer (flies under compute)
            if (kt + 1 < nkt) GLD_TILE(kb + 64, cur ^ 1);

            // QK^T: 16 rows x 64 cols
            fx4 sc[4];
#pragma unroll
            for (int nt = 0; nt < 4; ++nt) sc[nt] = zero4;
            __builtin_amdgcn_s_setprio(1);
#pragma unroll
            for (int c = 0; c < 4; ++c)
#pragma unroll
                for (int nt = 0; nt < 4; ++nt) {
                    int e = (nt * 16 + m16) * 128 + c * 32 + quad * 8;
                    bf16x8 kf =
                        *(const bf16x8*)&Ks[cur][e ^ ((m16 & 7) << 3)];
                    sc[nt] = MFMA16(qf[c], kf, sc[nt]);
                }
            __builtin_amdgcn_s_setprio(0);

            // shuffle online softmax (row = quad*4+r, its 16 cols on lanes
            // quad*16..quad*16+15; xor 1/2/4/8 stays inside the group)
#pragma unroll
            for (int r = 0; r < 4; ++r) {
                int rg = qrow0 + quad * 4 + r;
                float mx = mi[r];
#pragma unroll
                for (int nt = 0; nt < 4; ++nt) {
                    int cg = kb + nt * 16 + m16;
                    float s = sc[nt][r] * scale;
                    s = (cg <= rg) ? s : -1e30f;
                    sc[nt][r] = s;
                    mx = fmaxf(mx, s);
                }
                mx = fmaxf(mx, __shfl_xor(mx, 1));
                mx = fmaxf(mx, __shfl_xor(mx, 2));
                mx = fmaxf(mx, __shfl_xor(mx, 4));
                mx = fmaxf(mx, __shfl_xor(mx, 8));
                float alpha = __expf(mi[r] - mx);
                mi[r] = mx;
                float rsum = 0.f;
                int row = quad * 4 + r;
#pragma unroll
                for (int nt = 0; nt < 4; ++nt) {
                    float p = __expf(sc[nt][r] - mx);
                    Ps[wave][(row * 64 + nt * 16 + m16) ^ ((row & 7) << 3)] =
                        f2bf(p);
                    rsum += p;
                }
                rsum += __shfl_xor(rsum, 1);
                rsum += __shfl_xor(rsum, 2);
                rsum += __shfl_xor(rsum, 4);
                rsum += __shfl_xor(rsum, 8);
                li[r] = li[r] * alpha + rsum;
#pragma unroll
                for (int dn = 0; dn < 8; ++dn) o[dn][r] *= alpha;
            }

            // O += P * V. Ps wave-private: same-wave ds ordering suffices.
            __builtin_amdgcn_s_setprio(1);
#pragma unroll
            for (int c2 = 0; c2 < 2; ++c2) {
                bf16x8 pf = *(const bf16x8*)&Ps[wave][(m16 * 64 + c2 * 32 +
                                                       quad * 8) ^
                                                      ((m16 & 7) << 3)];
#pragma unroll
                for (int dn = 0; dn < 8; ++dn) {
                    int e = (dn * 16 + m16) * 64 + c2 * 32 + quad * 8;
                    bf16x8 vf =
                        *(const bf16x8*)&Vs[cur][e ^ ((m16 & 7) << 3)];
                    o[dn] = MFMA16(pf, vf, o[dn]);
                }
            }
            __builtin_amdgcn_s_setprio(0);

            __syncthreads();  // drains prefetch; ends reads of buf cur
            cur ^= 1;
        }

        // epilogue for this pass's 16 rows
#pragma unroll
        for (int r = 0; r < 4; ++r) {
            int row = qrow0 + quad * 4 + r;
            float inv = 1.0f / li[r];
#pragma unroll
            for (int dn = 0; dn < 8; ++dn) {
                int d = dn * 16 + m16;
                ctx[((size_t)(b * 2048 + row)) * 2048 + h * 128 + d] =
                    f2bf(o[dn][r] * inv);
            }
        }
    }
}

// ---------------------------------------------------------------------------
// ws (64 MiB u16): xb 8388608 | wqkvb 12582912 | v/ctx 8388608 | outwb 4194304
// d_out (32 MiB used as scratch until final GEMM): q 8388608 | k 8388608
// vt reuses xb after the QKV GEMM. Final GEMM overwrites d_out (q,k dead).
// ---------------------------------------------------------------------------
extern "C" void kernel_launch(void* const* d_in, const int* in_sizes, int n_in,
                              void* d_out, int out_size, void* d_ws,
                              size_t ws_size, hipStream_t stream) {
    const float* x = (const float*)d_in[0];
    const float* wqkv_w = (const float*)d_in[1];
    const float* wqkv_b = (const float*)d_in[2];
    const float* out_w = (const float*)d_in[3];
    const float* out_b = (const float*)d_in[4];
    u16* ws = (u16*)d_ws;

    u16* xb = ws;                   // 8388608 u16 (later: vt)
    u16* wqkvb = ws + 8388608;      // 12582912 u16
    u16* vb = ws + 20971520;        // 8388608 u16 (later: ctx)
    u16* outwb = ws + 29360128;     // 4194304 u16
    u16* vtb = xb;
    u16* ctx = vb;
    u16* qb = (u16*)d_out;          // 8388608 u16
    u16* kb = qb + 8388608;         // 8388608 u16

    cvt_kernel<<<12288, 256, 0, stream>>>(x, wqkv_w, out_w, xb, wqkvb, outwb);
    gemm_bt<1><<<dim3(48, 32), 256, 0, stream>>>(xb, wqkvb, wqkv_b, nullptr,
                                                 qb, kb, vb, 6144, 2048);
    rope_kernel<<<16384, 256, 0, stream>>>(qb, kb);
    vtrans_kernel<<<dim3(32, 32), 256, 0, stream>>>(vb, vtb);
    attn_kernel<<<512, 256, 0, stream>>>(qb, kb, vtb, ctx);
    gemm_bt<0><<<dim3(16, 32), 256, 0, stream>>>(ctx, outwb, out_b,
                                                 (float*)d_out, nullptr,
                                                 nullptr, nullptr, 2048, 2048);
}